// Round 10
// baseline (373.629 us; speedup 1.0000x reference)
//
#include <hip/hip_runtime.h>
#include <cmath>

// EmbedMaskPostProcessor: top-k select + box decode + embedding-distance masks.
// Output [2,200,384,384] f32 = 236 MB, <1% nonzero -> write-BW bound (~34us floor).
// R10: persistent-block single kernel. 512 blocks (provably co-resident at
// __launch_bounds__(256,2): 2/CU x 256 CU), so global spin barriers are safe
// under ANY dispatch order. Blocks 0-255 do selection while all 512 drain a
// ticket pool of 96KB zero tiles (selection hides under the 34us write stream);
// global barrier; blocks 0-399 patch box values over the zeros (store-store
// order via AGENT release/acquire = L2 writeback on multi-XCD).

namespace {
constexpr int NIMG = 2;
constexpr int NC   = 80;
constexpr int NHW  = 96 * 96;        // 9216
constexpr int NCHW = NC * NHW;       // 737280
constexpr int NDIM = 32;
constexpr int PH = 192, PW = 192;    // pixel_embed spatial
constexpr int OH = 384, OW = 384;    // output mask spatial
constexpr int KTOP = 200;
constexpr int CAP = 4096;            // gathered band candidates per image
constexpr int MCAP = 1024;           // member cap after 27-bit refine
constexpr int LCAP = 512;            // per-block gather buffer
constexpr float PRE_THRESH = 0.05f;
constexpr unsigned KEY_ZERO = 0x80000000u;  // key of +0.0f; key > this <=> value > 0
constexpr float IMG_MAX = 767.0f;

constexpr int NBOX = NIMG * KTOP;    // 400
constexpr int ZTILES = 6;            // 64-row tiles per (n,k)
constexpr int NTILES = NBOX * ZTILES;// 2400 zero tiles, 96 KB each
constexpr int TILE_F4 = 64 * OW / 4; // 6144 float4 per tile

constexpr int NF4 = NCHW / 4;        // 184320
constexpr int SEL_BLOCKS = 128;      // selection blocks per image
constexpr int NSEL = 2 * SEL_BLOCKS; // 256
constexpr int GRID = 512;            // 2 blocks/CU x 256 CU -> co-resident
constexpr int SEL_STRIDE = SEL_BLOCKS * 256;                    // 32768
constexpr int SEL_ITERS = (NF4 + SEL_STRIDE - 1) / SEL_STRIDE;  // 6

// ws layout (4-byte words)
constexpr int WS_HIST1 = 0;                          // [NIMG][2048]
constexpr int WS_CNT   = WS_HIST1 + NIMG * 2048;     // [NIMG]
constexpr int WS_BAR1  = WS_CNT + NIMG;              // [1] sel barrier
constexpr int WS_BAR2  = WS_BAR1 + 1;                // [1] global barrier
constexpr int WS_TICK  = WS_BAR2 + 1;                // [NIMG] last-sel tickets
constexpr int WS_POOL  = WS_TICK + NIMG;             // [1] zero-tile ticket
constexpr int WS_ZERO_WORDS = WS_POOL + 1;
constexpr int WS_PAIRS = 4104;                       // [NIMG][CAP][2] {key,ref}
constexpr int WS_PARAMS = WS_PAIRS + NIMG * CAP * 2; // [NIMG][KTOP][40]
constexpr int PARAM_WORDS = 40;  // [0]=valid [1..4]=ix0,ix1,iy0,iy1 [5]=margin [8..39]=e

typedef float f4 __attribute__((ext_vector_type(4)));
}

__device__ __forceinline__ unsigned key_of(float f) {
  unsigned u = __float_as_uint(f);
  return (u & 0x80000000u) ? ~u : (u | 0x80000000u);  // monotone: bigger float -> bigger key
}
__device__ __forceinline__ unsigned aget(const unsigned* p) {
  return __hip_atomic_load(p, __ATOMIC_RELAXED, __HIP_MEMORY_SCOPE_AGENT);
}
__device__ __forceinline__ void aput(unsigned* p, unsigned v) {
  __hip_atomic_store(p, v, __ATOMIC_RELAXED, __HIP_MEMORY_SCOPE_AGENT);
}

// Zero hist/counters/barriers.
__global__ __launch_bounds__(256) void k_zero_ws(unsigned* __restrict__ ws) {
  for (int j = threadIdx.x; j < WS_ZERO_WORDS; j += 256) ws[j] = 0u;
}

__global__ __launch_bounds__(256, 2) void k_main(
    const float* __restrict__ box_cls, const float* __restrict__ ctrness,
    const float* __restrict__ locations, const float* __restrict__ box_reg,
    const float* __restrict__ pemb, const float* __restrict__ pmar,
    const float* __restrict__ pix,
    unsigned* __restrict__ ws, float* __restrict__ out) {
  const int t = threadIdx.x;
  const int bid = blockIdx.x;
  __shared__ unsigned hist[2048];          // 8 KB: phase1 hist / phase2 scan scratch
  __shared__ unsigned sh_sum[256];
  __shared__ int sh_bk[2];
  __shared__ unsigned loc[LCAP][2];        // 4 KB
  __shared__ unsigned mKey[MCAP], mRef[MCAP];  // 8 KB
  __shared__ unsigned h256[256];
  __shared__ int lcnt, sh_last, sh_b, sh_t2, sh_tk;
  __shared__ unsigned gbase;

  if (bid < NSEL) {
    // ======== selection (R8 pipeline, LDS-slim phase 3) ========
    const int n = bid >= SEL_BLOCKS;
    const int bi = bid - n * SEL_BLOCKS;

    // ---- phase 1: keygen into registers + LDS hist (positives only) ----
    for (int i = t; i < 2048; i += 256) hist[i] = 0;
    __syncthreads();
    const float* cls = box_cls + n * NCHW;
    const float* ctr = ctrness + n * NHW;
    unsigned kk[SEL_ITERS][4];
    #pragma unroll
    for (int s = 0; s < SEL_ITERS; ++s) {
      const int j4 = s * SEL_STRIDE + bi * 256 + t;
      if (j4 < NF4) {
        const int j = j4 * 4;
        const int c = j / NHW;
        const int hw = j - c * NHW;                        // multiple of 4
        const f4 xv = *reinterpret_cast<const f4*>(cls + j);
        const f4 cv = *reinterpret_cast<const f4*>(ctr + hw);
        #pragma unroll
        for (int q = 0; q < 4; ++q) {
          const float sg = 1.0f / (1.0f + expf(-xv[q]));
          float v = -1.0f;
          if (sg > PRE_THRESH) v = sg * (1.0f / (1.0f + expf(-cv[q])));
          const unsigned k = key_of(v);
          kk[s][q] = k;
          if (k > KEY_ZERO) atomicAdd(&hist[k >> 21], 1u);
        }
      } else {
        #pragma unroll
        for (int q = 0; q < 4; ++q) kk[s][q] = 0u;
      }
    }
    __syncthreads();
    {
      unsigned* gh = ws + WS_HIST1 + n * 2048;
      for (int i = t; i < 2048; i += 256) { unsigned v = hist[i]; if (v) atomicAdd(&gh[i], v); }
    }

    // ---- barrier 1: the 256 sel blocks (co-resident: 256 < GRID capacity) ----
    __syncthreads();
    if (t == 0) {
      __hip_atomic_fetch_add(ws + WS_BAR1, 1u, __ATOMIC_ACQ_REL, __HIP_MEMORY_SCOPE_AGENT);
      while (__hip_atomic_load(ws + WS_BAR1, __ATOMIC_ACQUIRE,
                               __HIP_MEMORY_SCOPE_AGENT) < (unsigned)NSEL) {
        __builtin_amdgcn_s_sleep(8);
      }
    }
    __syncthreads();

    // ---- phase 2: scan global hist for b1/krem ----
    if (t == 0) { sh_bk[0] = -1; sh_bk[1] = KTOP; }
    {
      const unsigned* gh = ws + WS_HIST1 + n * 2048;
      unsigned local = 0;
      for (int j = 0; j < 8; ++j) { unsigned v = gh[t * 8 + j]; hist[t * 8 + j] = v; local += v; }
      sh_sum[t] = local;
    }
    __syncthreads();
    {
      unsigned S = 0;
      for (int j = t + 1; j < 256; ++j) S += sh_sum[j];
      int cand_b = -1;
      unsigned cand_above = 0;
      unsigned run = S;
      for (int j = 7; j >= 0; --j) {
        const unsigned cv = hist[t * 8 + j];
        if (cand_b < 0 && run + cv >= (unsigned)KTOP) { cand_b = t * 8 + j; cand_above = run; }
        run += cv;
      }
      if (cand_b >= 0) atomicMax(&sh_bk[0], cand_b);
      __syncthreads();
      if (cand_b >= 0 && cand_b == sh_bk[0]) sh_bk[1] = KTOP - (int)cand_above;
      __syncthreads();
    }
    const unsigned b1 = (unsigned)(sh_bk[0] < 0 ? 0 : sh_bk[0]);
    int krem = sh_bk[1];

    // ---- gather band members: regs -> LDS -> one global reservation ----
    if (t == 0) lcnt = 0;
    __syncthreads();
    #pragma unroll
    for (int s = 0; s < SEL_ITERS; ++s) {
      #pragma unroll
      for (int q = 0; q < 4; ++q) {
        const unsigned k = kk[s][q];
        if ((k >> 21) < b1) continue;
        const int j = (s * SEL_STRIDE + bi * 256 + t) * 4 + q;
        const int c = j / NHW;
        const int hw = j - c * NHW;
        const int p = atomicAdd(&lcnt, 1);
        if (p < LCAP) { loc[p][0] = k; loc[p][1] = (unsigned)(hw * NC + c); }
      }
    }
    __syncthreads();
    const int lc = min(lcnt, LCAP);
    if (t == 0) gbase = atomicAdd(ws + WS_CNT + n, (unsigned)lc);
    __syncthreads();
    for (int i = t; i < lc; i += 256) {
      const unsigned pos = gbase + (unsigned)i;
      if (pos < (unsigned)CAP) {
        aput(&ws[WS_PAIRS + (n * CAP + (int)pos) * 2], loc[i][0]);
        aput(&ws[WS_PAIRS + (n * CAP + (int)pos) * 2 + 1], loc[i][1]);
      }
    }

    // ---- per-image last-block ticket ----
    __syncthreads();
    if (t == 0) {
      const unsigned old = atomicAdd(ws + WS_TICK + n, 1u);
      sh_last = (old == (unsigned)(SEL_BLOCKS - 1)) ? 1 : 0;
    }
    __syncthreads();

    if (sh_last) {
      // ---- phase 3: refine to 27-bit prefix (pairs read from L2, no LDS
      //      staging), compact members, exact rank, emit params ----
      for (int s = t; s < KTOP; s += 256) aput(&ws[WS_PARAMS + (n * KTOP + s) * PARAM_WORDS], 0u);
      const int cnt = min((int)aget(ws + WS_CNT + n), CAP);
      unsigned prefix = b1;
      int shift = 21;
      #pragma unroll
      for (int level = 0; level < 2; ++level) {
        const int newshift = shift - 8;
        h256[t] = 0;
        if (t == 0) sh_b = 0;
        __syncthreads();
        for (int i = t; i < cnt; i += 256) {
          const unsigned k = aget(&ws[WS_PAIRS + (n * CAP + i) * 2]);
          if ((k >> shift) == prefix) atomicAdd(&h256[(k >> newshift) & 255u], 1u);
        }
        __syncthreads();
        const unsigned hv = h256[t];
        unsigned S = 0;
        for (int j = t + 1; j < 256; ++j) S += h256[j];
        if (S + hv >= (unsigned)krem) atomicMax(&sh_b, t);
        __syncthreads();
        const int b = sh_b;
        if (t == b) sh_t2 = krem - (int)S;
        __syncthreads();
        krem = sh_t2;
        prefix = (prefix << 8) | (unsigned)b;
        shift = newshift;
        __syncthreads();
      }

      if (t == 0) sh_t2 = 0;
      __syncthreads();
      for (int i = t; i < cnt; i += 256) {
        const unsigned k = aget(&ws[WS_PAIRS + (n * CAP + i) * 2]);
        if ((k >> 5) >= prefix) {
          const int pos = atomicAdd(&sh_t2, 1);
          if (pos < MCAP) { mKey[pos] = k; mRef[pos] = aget(&ws[WS_PAIRS + (n * CAP + i) * 2 + 1]); }
        }
      }
      __syncthreads();
      const int m = min(sh_t2, MCAP);

      for (int i = t; i < m; i += 256) {
        const unsigned ki = mKey[i], ri = mRef[i];
        int rank = 0;
        for (int j = 0; j < m; ++j) {
          const unsigned kj = mKey[j], rj = mRef[j];
          rank += (kj > ki || (kj == ki && rj < ri)) ? 1 : 0;
        }
        if (rank >= KTOP) continue;
        unsigned* pp = ws + WS_PARAMS + (n * KTOP + rank) * PARAM_WORDS;
        int valid = 0;
        if (ki > KEY_ZERO) {
          const int hw = (int)ri / NC;
          const float lx = locations[2 * hw], ly = locations[2 * hw + 1];
          const float rl = box_reg[(n * 4 + 0) * NHW + hw];
          const float rt = box_reg[(n * 4 + 1) * NHW + hw];
          const float rr = box_reg[(n * 4 + 2) * NHW + hw];
          const float rb = box_reg[(n * 4 + 3) * NHW + hw];
          const float x1 = fminf(fmaxf(lx - rl, 0.f), IMG_MAX);
          const float y1 = fminf(fmaxf(ly - rt, 0.f), IMG_MAX);
          const float x2 = fminf(fmaxf(lx + rr, 0.f), IMG_MAX);
          const float y2 = fminf(fmaxf(ly + rb, 0.f), IMG_MAX);
          const int ix0 = max(0, (int)ceilf(x1 * 0.25f));
          const int ix1 = min(OW - 1, (int)floorf(x2 * 0.25f));
          const int iy0 = max(0, (int)ceilf(y1 * 0.25f));
          const int iy1 = min(OH - 1, (int)floorf(y2 * 0.25f));
          if (ix0 <= ix1 && iy0 <= iy1) {
            valid = 1;
            aput(pp + 1, (unsigned)ix0); aput(pp + 2, (unsigned)ix1);
            aput(pp + 3, (unsigned)iy0); aput(pp + 4, (unsigned)iy1);
            aput(pp + 5, __float_as_uint(pmar[n * NHW + hw]));
            #pragma unroll
            for (int d = 0; d < NDIM; ++d)
              aput(pp + 8 + d, __float_as_uint(pemb[(n * NDIM + d) * NHW + hw]));
          }
        }
        aput(pp + 0, (unsigned)valid);
      }
      __syncthreads();
    }
  }

  // ======== all 512 blocks: drain zero-tile pool (96 KB tiles) ========
  {
    const f4 z = {0.f, 0.f, 0.f, 0.f};
    for (;;) {
      if (t == 0) sh_tk = (int)atomicAdd(ws + WS_POOL, 1u);
      __syncthreads();
      const int tk = sh_tk;
      __syncthreads();
      if (tk >= NTILES) break;
      f4* ob4 = reinterpret_cast<f4*>(out) + (size_t)tk * TILE_F4;
      #pragma unroll
      for (int i = 0; i < 24; ++i) ob4[i * 256 + t] = z;
    }
  }

  // ======== barrier 2: all GRID blocks (co-resident by __launch_bounds__(256,2)) ========
  __syncthreads();
  if (t == 0) {
    __hip_atomic_fetch_add(ws + WS_BAR2, 1u, __ATOMIC_ACQ_REL, __HIP_MEMORY_SCOPE_AGENT);
    while (__hip_atomic_load(ws + WS_BAR2, __ATOMIC_ACQUIRE,
                             __HIP_MEMORY_SCOPE_AGENT) < (unsigned)GRID) {
      __builtin_amdgcn_s_sleep(8);
    }
  }
  __syncthreads();

  // ======== patch: blocks [0, NBOX) write box values over the zeros ========
  if (bid >= NBOX) return;
  const int nk = bid;
  const unsigned* meta = ws + WS_PARAMS + nk * PARAM_WORDS;
  if (aget(meta) == 0u) return;
  const int ix0 = (int)aget(meta + 1), ix1 = (int)aget(meta + 2);
  const int iy0 = (int)aget(meta + 3), iy1 = (int)aget(meta + 4);
  const float margin = __uint_as_float(aget(meta + 5));
  float e[NDIM];
  #pragma unroll
  for (int d = 0; d < NDIM; ++d) e[d] = __uint_as_float(aget(meta + 8 + d));
  const int n2 = nk / KTOP;
  const float* peb = pix + (size_t)n2 * NDIM * PH * PW;
  float* ob = out + (size_t)nk * (OH * OW);

  const int tx = t & 63;             // column lane
  const int ts = t >> 6;             // row strip 0..3
  const int h = iy1 - iy0 + 1;
  const int shh = (h + 3) >> 2;
  const int ybeg = iy0 + ts * shh;
  const int yend = min(iy0 + (ts + 1) * shh, iy1 + 1);

  for (int c = ix0 + tx; c <= ix1; c += 64) {
    const float sx = 0.5f * (float)c - 0.25f;
    const float xf = floorf(sx);
    const float fx = sx - xf;
    const int xs0 = max((int)xf, 0);
    const int xs1 = min((int)xf + 1, PW - 1);
    float qa_[NDIM], qb_[NDIM];
    int ra = -9, rb = -9;
    for (int y = ybeg; y < yend; ++y) {
      const float sy = 0.5f * (float)y - 0.25f;
      const float yf = floorf(sy);
      const float fy = sy - yf;
      const int ys0 = max((int)yf, 0);
      const int ys1 = min((int)yf + 1, PH - 1);
      if (ys0 != ra) {
        if (ys0 == rb) {
          #pragma unroll
          for (int d = 0; d < NDIM; ++d) qa_[d] = qb_[d];
        } else {
          const float* p = peb + (size_t)ys0 * PW;
          #pragma unroll
          for (int d = 0; d < NDIM; ++d)
            qa_[d] = (1.f - fx) * p[d * PH * PW + xs0] + fx * p[d * PH * PW + xs1];
        }
        ra = ys0;
      }
      if (ys1 != rb) {
        if (ys1 == ra) {
          #pragma unroll
          for (int d = 0; d < NDIM; ++d) qb_[d] = qa_[d];
        } else {
          const float* p = peb + (size_t)ys1 * PW;
          #pragma unroll
          for (int d = 0; d < NDIM; ++d)
            qb_[d] = (1.f - fx) * p[d * PH * PW + xs0] + fx * p[d * PH * PW + xs1];
        }
        rb = ys1;
      }
      float d2 = 0.f;
      #pragma unroll
      for (int d = 0; d < NDIM; ++d) {
        const float pv = qa_[d] + fy * (qb_[d] - qa_[d]);
        const float df = e[d] - pv;
        d2 = fmaf(df, df, d2);
      }
      ob[(size_t)y * OW + c] = expf(-d2 * margin);
    }
  }
}

extern "C" void kernel_launch(void* const* d_in, const int* in_sizes, int n_in,
                              void* d_out, int out_size, void* d_ws, size_t ws_size,
                              hipStream_t stream) {
  const float* locations = (const float*)d_in[0];
  const float* box_cls   = (const float*)d_in[1];
  const float* box_reg   = (const float*)d_in[2];
  const float* ctrness   = (const float*)d_in[3];
  const float* pemb      = (const float*)d_in[4];
  const float* pmar      = (const float*)d_in[5];
  const float* pix       = (const float*)d_in[6];
  float* out = (float*)d_out;
  unsigned* ws = (unsigned*)d_ws;

  k_zero_ws<<<dim3(1), dim3(256), 0, stream>>>(ws);
  k_main   <<<dim3(GRID), dim3(256), 0, stream>>>(
      box_cls, ctrness, locations, box_reg, pemb, pmar, pix, ws, out);
}

// Round 11
// 199.954 us; speedup vs baseline: 1.8686x; 1.8686x over previous
//
#include <hip/hip_runtime.h>
#include <cmath>

// EmbedMaskPostProcessor: top-k select + box decode + embedding-distance masks.
// Output [2,200,384,384] f32 = 236 MB, <1% nonzero -> write-BW bound (~34us floor).
// R11 = R10 overlap structure with corrected atomics:
//   - spins are RELAXED (R10's ACQUIRE spin emitted an L2-invalidate per
//     iteration -> 0.5 TB/s write collapse; R8 proved relaxed spins are free)
//   - cross-block scalars (hist/pairs/meta) move via sc1-bypass relaxed agent
//     atomics (never dirty in any L2 -> no fences needed to read)
//   - barrier-2 arrive is RELEASE (one wbl2/block): writes back each XCD's
//     dirty zero-lines BEFORE patch blocks overwrite same lines from other
//     XCDs (WAW through non-coherent L2s needs this; it's also why R10 passed)

namespace {
constexpr int NIMG = 2;
constexpr int NC   = 80;
constexpr int NHW  = 96 * 96;        // 9216
constexpr int NCHW = NC * NHW;       // 737280
constexpr int NDIM = 32;
constexpr int PH = 192, PW = 192;    // pixel_embed spatial
constexpr int OH = 384, OW = 384;    // output mask spatial
constexpr int KTOP = 200;
constexpr int CAP = 4096;            // gathered band candidates per image
constexpr int MCAP = 1024;           // member cap after 27-bit refine
constexpr int LCAP = 512;            // per-block gather buffer
constexpr float PRE_THRESH = 0.05f;
constexpr unsigned KEY_ZERO = 0x80000000u;  // key of +0.0f
constexpr float IMG_MAX = 767.0f;

constexpr int NBOX = NIMG * KTOP;    // 400
constexpr int ZTILES = 6;            // 64-row tiles per (n,k)
constexpr int NTILES = NBOX * ZTILES;// 2400 zero tiles, 96 KB each
constexpr int TILE_F4 = 64 * OW / 4; // 6144 float4 per tile

constexpr int NF4 = NCHW / 4;        // 184320
constexpr int SEL_BLOCKS = 128;      // selection blocks per image
constexpr int NSEL = 2 * SEL_BLOCKS; // 256
constexpr int GRID = 512;            // 2 blocks/CU x 256 CU -> co-resident
constexpr int SEL_STRIDE = SEL_BLOCKS * 256;                    // 32768
constexpr int SEL_ITERS = (NF4 + SEL_STRIDE - 1) / SEL_STRIDE;  // 6

// ws layout (4-byte words)
constexpr int WS_HIST1 = 0;                          // [NIMG][2048]
constexpr int WS_CNT   = WS_HIST1 + NIMG * 2048;     // [NIMG]
constexpr int WS_BAR1  = WS_CNT + NIMG;              // [1] sel barrier
constexpr int WS_BAR2  = WS_BAR1 + 1;                // [1] global barrier
constexpr int WS_TICK  = WS_BAR2 + 1;                // [NIMG] last-sel tickets
constexpr int WS_POOL  = WS_TICK + NIMG;             // [1] zero-tile ticket
constexpr int WS_ZERO_WORDS = WS_POOL + 1;
constexpr int WS_PAIRS = 4104;                       // [NIMG][CAP][2] {key,ref}
constexpr int WS_PARAMS = WS_PAIRS + NIMG * CAP * 2; // [NIMG][KTOP][40]
constexpr int PARAM_WORDS = 40;  // [0]=valid [1..4]=ix0,ix1,iy0,iy1 [5]=margin [8..39]=e

typedef float f4 __attribute__((ext_vector_type(4)));
}

__device__ __forceinline__ unsigned key_of(float f) {
  unsigned u = __float_as_uint(f);
  return (u & 0x80000000u) ? ~u : (u | 0x80000000u);  // monotone: bigger float -> bigger key
}
// sc1-bypass relaxed agent ops: read/write the device coherence point, never
// leave dirty or rely on clean lines in any per-XCD L2.
__device__ __forceinline__ unsigned aget(const unsigned* p) {
  return __hip_atomic_load(p, __ATOMIC_RELAXED, __HIP_MEMORY_SCOPE_AGENT);
}
__device__ __forceinline__ void aput(unsigned* p, unsigned v) {
  __hip_atomic_store(p, v, __ATOMIC_RELAXED, __HIP_MEMORY_SCOPE_AGENT);
}

// Zero hist/counters/barriers via bypass stores (no stale clean lines anywhere).
__global__ __launch_bounds__(256) void k_zero_ws(unsigned* __restrict__ ws) {
  for (int j = threadIdx.x; j < WS_ZERO_WORDS; j += 256) aput(ws + j, 0u);
}

__global__ __launch_bounds__(256, 2) void k_main(
    const float* __restrict__ box_cls, const float* __restrict__ ctrness,
    const float* __restrict__ locations, const float* __restrict__ box_reg,
    const float* __restrict__ pemb, const float* __restrict__ pmar,
    const float* __restrict__ pix,
    unsigned* __restrict__ ws, float* __restrict__ out) {
  const int t = threadIdx.x;
  const int bid = blockIdx.x;
  __shared__ unsigned hist[2048];          // 8 KB
  __shared__ unsigned sh_sum[256];
  __shared__ int sh_bk[2];
  __shared__ unsigned loc[LCAP][2];        // 4 KB
  __shared__ unsigned mKey[MCAP], mRef[MCAP];  // 8 KB
  __shared__ unsigned h256[256];
  __shared__ int lcnt, sh_last, sh_b, sh_t2, sh_tk;
  __shared__ unsigned gbase;

  if (bid < NSEL) {
    // ======== selection (R8 pipeline) ========
    const int n = bid >= SEL_BLOCKS;
    const int bi = bid - n * SEL_BLOCKS;

    // ---- phase 1: keygen into registers + LDS hist (positives only) ----
    for (int i = t; i < 2048; i += 256) hist[i] = 0;
    __syncthreads();
    const float* cls = box_cls + n * NCHW;
    const float* ctr = ctrness + n * NHW;
    unsigned kk[SEL_ITERS][4];
    #pragma unroll
    for (int s = 0; s < SEL_ITERS; ++s) {
      const int j4 = s * SEL_STRIDE + bi * 256 + t;
      if (j4 < NF4) {
        const int j = j4 * 4;
        const int c = j / NHW;
        const int hw = j - c * NHW;                        // multiple of 4
        const f4 xv = *reinterpret_cast<const f4*>(cls + j);
        const f4 cv = *reinterpret_cast<const f4*>(ctr + hw);
        #pragma unroll
        for (int q = 0; q < 4; ++q) {
          const float sg = 1.0f / (1.0f + expf(-xv[q]));
          float v = -1.0f;
          if (sg > PRE_THRESH) v = sg * (1.0f / (1.0f + expf(-cv[q])));
          const unsigned k = key_of(v);
          kk[s][q] = k;
          if (k > KEY_ZERO) atomicAdd(&hist[k >> 21], 1u);
        }
      } else {
        #pragma unroll
        for (int q = 0; q < 4; ++q) kk[s][q] = 0u;
      }
    }
    __syncthreads();
    {
      unsigned* gh = ws + WS_HIST1 + n * 2048;
      for (int i = t; i < 2048; i += 256) { unsigned v = hist[i]; if (v) atomicAdd(&gh[i], v); }
    }

    // ---- barrier 1 (sel blocks only): RELAXED spin, no cache maintenance ----
    __syncthreads();
    if (t == 0) {
      atomicAdd(ws + WS_BAR1, 1u);
      while (aget(ws + WS_BAR1) < (unsigned)NSEL) __builtin_amdgcn_s_sleep(8);
    }
    __syncthreads();

    // ---- phase 2: scan global hist (bypass loads) for b1/krem ----
    if (t == 0) { sh_bk[0] = -1; sh_bk[1] = KTOP; }
    {
      const unsigned* gh = ws + WS_HIST1 + n * 2048;
      unsigned local = 0;
      for (int j = 0; j < 8; ++j) { unsigned v = aget(gh + t * 8 + j); hist[t * 8 + j] = v; local += v; }
      sh_sum[t] = local;
    }
    __syncthreads();
    {
      unsigned S = 0;
      for (int j = t + 1; j < 256; ++j) S += sh_sum[j];
      int cand_b = -1;
      unsigned cand_above = 0;
      unsigned run = S;
      for (int j = 7; j >= 0; --j) {
        const unsigned cv = hist[t * 8 + j];
        if (cand_b < 0 && run + cv >= (unsigned)KTOP) { cand_b = t * 8 + j; cand_above = run; }
        run += cv;
      }
      if (cand_b >= 0) atomicMax(&sh_bk[0], cand_b);
      __syncthreads();
      if (cand_b >= 0 && cand_b == sh_bk[0]) sh_bk[1] = KTOP - (int)cand_above;
      __syncthreads();
    }
    const unsigned b1 = (unsigned)(sh_bk[0] < 0 ? 0 : sh_bk[0]);
    int krem = sh_bk[1];

    // ---- gather band members: regs -> LDS -> one global reservation ----
    if (t == 0) lcnt = 0;
    __syncthreads();
    #pragma unroll
    for (int s = 0; s < SEL_ITERS; ++s) {
      #pragma unroll
      for (int q = 0; q < 4; ++q) {
        const unsigned k = kk[s][q];
        if ((k >> 21) < b1) continue;
        const int j = (s * SEL_STRIDE + bi * 256 + t) * 4 + q;
        const int c = j / NHW;
        const int hw = j - c * NHW;
        const int p = atomicAdd(&lcnt, 1);
        if (p < LCAP) { loc[p][0] = k; loc[p][1] = (unsigned)(hw * NC + c); }
      }
    }
    __syncthreads();
    const int lc = min(lcnt, LCAP);
    if (t == 0) gbase = atomicAdd(ws + WS_CNT + n, (unsigned)lc);
    __syncthreads();
    for (int i = t; i < lc; i += 256) {
      const unsigned pos = gbase + (unsigned)i;
      if (pos < (unsigned)CAP) {
        aput(&ws[WS_PAIRS + (n * CAP + (int)pos) * 2], loc[i][0]);
        aput(&ws[WS_PAIRS + (n * CAP + (int)pos) * 2 + 1], loc[i][1]);
      }
    }

    // ---- per-image last-block ticket ----
    __syncthreads();
    if (t == 0) {
      const unsigned old = atomicAdd(ws + WS_TICK + n, 1u);
      sh_last = (old == (unsigned)(SEL_BLOCKS - 1)) ? 1 : 0;
    }
    __syncthreads();

    if (sh_last) {
      // ---- phase 3: refine to 27-bit prefix, compact, exact rank, emit ----
      for (int s = t; s < KTOP; s += 256) aput(&ws[WS_PARAMS + (n * KTOP + s) * PARAM_WORDS], 0u);
      const int cnt = min((int)aget(ws + WS_CNT + n), CAP);
      unsigned prefix = b1;
      int shift = 21;
      #pragma unroll
      for (int level = 0; level < 2; ++level) {
        const int newshift = shift - 8;
        h256[t] = 0;
        if (t == 0) sh_b = 0;
        __syncthreads();
        for (int i = t; i < cnt; i += 256) {
          const unsigned k = aget(&ws[WS_PAIRS + (n * CAP + i) * 2]);
          if ((k >> shift) == prefix) atomicAdd(&h256[(k >> newshift) & 255u], 1u);
        }
        __syncthreads();
        const unsigned hv = h256[t];
        unsigned S = 0;
        for (int j = t + 1; j < 256; ++j) S += h256[j];
        if (S + hv >= (unsigned)krem) atomicMax(&sh_b, t);
        __syncthreads();
        const int b = sh_b;
        if (t == b) sh_t2 = krem - (int)S;
        __syncthreads();
        krem = sh_t2;
        prefix = (prefix << 8) | (unsigned)b;
        shift = newshift;
        __syncthreads();
      }

      if (t == 0) sh_t2 = 0;
      __syncthreads();
      for (int i = t; i < cnt; i += 256) {
        const unsigned k = aget(&ws[WS_PAIRS + (n * CAP + i) * 2]);
        if ((k >> 5) >= prefix) {
          const int pos = atomicAdd(&sh_t2, 1);
          if (pos < MCAP) { mKey[pos] = k; mRef[pos] = aget(&ws[WS_PAIRS + (n * CAP + i) * 2 + 1]); }
        }
      }
      __syncthreads();
      const int m = min(sh_t2, MCAP);

      for (int i = t; i < m; i += 256) {
        const unsigned ki = mKey[i], ri = mRef[i];
        int rank = 0;
        for (int j = 0; j < m; ++j) {
          const unsigned kj = mKey[j], rj = mRef[j];
          rank += (kj > ki || (kj == ki && rj < ri)) ? 1 : 0;
        }
        if (rank >= KTOP) continue;
        unsigned* pp = ws + WS_PARAMS + (n * KTOP + rank) * PARAM_WORDS;
        int valid = 0;
        if (ki > KEY_ZERO) {
          const int hw = (int)ri / NC;
          const float lx = locations[2 * hw], ly = locations[2 * hw + 1];
          const float rl = box_reg[(n * 4 + 0) * NHW + hw];
          const float rt = box_reg[(n * 4 + 1) * NHW + hw];
          const float rr = box_reg[(n * 4 + 2) * NHW + hw];
          const float rb = box_reg[(n * 4 + 3) * NHW + hw];
          const float x1 = fminf(fmaxf(lx - rl, 0.f), IMG_MAX);
          const float y1 = fminf(fmaxf(ly - rt, 0.f), IMG_MAX);
          const float x2 = fminf(fmaxf(lx + rr, 0.f), IMG_MAX);
          const float y2 = fminf(fmaxf(ly + rb, 0.f), IMG_MAX);
          const int ix0 = max(0, (int)ceilf(x1 * 0.25f));
          const int ix1 = min(OW - 1, (int)floorf(x2 * 0.25f));
          const int iy0 = max(0, (int)ceilf(y1 * 0.25f));
          const int iy1 = min(OH - 1, (int)floorf(y2 * 0.25f));
          if (ix0 <= ix1 && iy0 <= iy1) {
            valid = 1;
            aput(pp + 1, (unsigned)ix0); aput(pp + 2, (unsigned)ix1);
            aput(pp + 3, (unsigned)iy0); aput(pp + 4, (unsigned)iy1);
            aput(pp + 5, __float_as_uint(pmar[n * NHW + hw]));
            #pragma unroll
            for (int d = 0; d < NDIM; ++d)
              aput(pp + 8 + d, __float_as_uint(pemb[(n * NDIM + d) * NHW + hw]));
          }
        }
        aput(pp + 0, (unsigned)valid);
      }
      __syncthreads();
    }
  }

  // ======== all 512 blocks: drain zero-tile pool (96 KB tiles, plain stores) ========
  {
    const f4 z = {0.f, 0.f, 0.f, 0.f};
    for (;;) {
      if (t == 0) sh_tk = (int)atomicAdd(ws + WS_POOL, 1u);
      __syncthreads();
      const int tk = sh_tk;
      __syncthreads();
      if (tk >= NTILES) break;
      f4* ob4 = reinterpret_cast<f4*>(out) + (size_t)tk * TILE_F4;
      #pragma unroll
      for (int i = 0; i < 24; ++i) ob4[i * 256 + t] = z;
    }
  }

  // ======== barrier 2: arrive = RELEASE (one wbl2/block: flush dirty zero
  // lines so patch WAW from other XCDs lands after); spin = RELAXED ========
  __syncthreads();
  if (t == 0) {
    __hip_atomic_fetch_add(ws + WS_BAR2, 1u, __ATOMIC_RELEASE, __HIP_MEMORY_SCOPE_AGENT);
    while (aget(ws + WS_BAR2) < (unsigned)GRID) __builtin_amdgcn_s_sleep(8);
  }
  __syncthreads();

  // ======== patch: blocks [0, NBOX) write box values over the zeros ========
  if (bid >= NBOX) return;
  const int nk = bid;
  const unsigned* meta = ws + WS_PARAMS + nk * PARAM_WORDS;
  if (aget(meta) == 0u) return;
  const int ix0 = (int)aget(meta + 1), ix1 = (int)aget(meta + 2);
  const int iy0 = (int)aget(meta + 3), iy1 = (int)aget(meta + 4);
  const float margin = __uint_as_float(aget(meta + 5));
  float e[NDIM];
  #pragma unroll
  for (int d = 0; d < NDIM; ++d) e[d] = __uint_as_float(aget(meta + 8 + d));
  const int n2 = nk / KTOP;
  const float* peb = pix + (size_t)n2 * NDIM * PH * PW;
  float* ob = out + (size_t)nk * (OH * OW);

  const int tx = t & 63;             // column lane
  const int ts = t >> 6;             // row strip 0..3
  const int h = iy1 - iy0 + 1;
  const int shh = (h + 3) >> 2;
  const int ybeg = iy0 + ts * shh;
  const int yend = min(iy0 + (ts + 1) * shh, iy1 + 1);

  for (int c = ix0 + tx; c <= ix1; c += 64) {
    const float sx = 0.5f * (float)c - 0.25f;
    const float xf = floorf(sx);
    const float fx = sx - xf;
    const int xs0 = max((int)xf, 0);
    const int xs1 = min((int)xf + 1, PW - 1);
    float qa_[NDIM], qb_[NDIM];
    int ra = -9, rb = -9;
    for (int y = ybeg; y < yend; ++y) {
      const float sy = 0.5f * (float)y - 0.25f;
      const float yf = floorf(sy);
      const float fy = sy - yf;
      const int ys0 = max((int)yf, 0);
      const int ys1 = min((int)yf + 1, PH - 1);
      if (ys0 != ra) {
        if (ys0 == rb) {
          #pragma unroll
          for (int d = 0; d < NDIM; ++d) qa_[d] = qb_[d];
        } else {
          const float* p = peb + (size_t)ys0 * PW;
          #pragma unroll
          for (int d = 0; d < NDIM; ++d)
            qa_[d] = (1.f - fx) * p[d * PH * PW + xs0] + fx * p[d * PH * PW + xs1];
        }
        ra = ys0;
      }
      if (ys1 != rb) {
        if (ys1 == ra) {
          #pragma unroll
          for (int d = 0; d < NDIM; ++d) qb_[d] = qa_[d];
        } else {
          const float* p = peb + (size_t)ys1 * PW;
          #pragma unroll
          for (int d = 0; d < NDIM; ++d)
            qb_[d] = (1.f - fx) * p[d * PH * PW + xs0] + fx * p[d * PH * PW + xs1];
        }
        rb = ys1;
      }
      float d2 = 0.f;
      #pragma unroll
      for (int d = 0; d < NDIM; ++d) {
        const float pv = qa_[d] + fy * (qb_[d] - qa_[d]);
        const float df = e[d] - pv;
        d2 = fmaf(df, df, d2);
      }
      ob[(size_t)y * OW + c] = expf(-d2 * margin);
    }
  }
}

extern "C" void kernel_launch(void* const* d_in, const int* in_sizes, int n_in,
                              void* d_out, int out_size, void* d_ws, size_t ws_size,
                              hipStream_t stream) {
  const float* locations = (const float*)d_in[0];
  const float* box_cls   = (const float*)d_in[1];
  const float* box_reg   = (const float*)d_in[2];
  const float* ctrness   = (const float*)d_in[3];
  const float* pemb      = (const float*)d_in[4];
  const float* pmar      = (const float*)d_in[5];
  const float* pix       = (const float*)d_in[6];
  float* out = (float*)d_out;
  unsigned* ws = (unsigned*)d_ws;

  k_zero_ws<<<dim3(1), dim3(256), 0, stream>>>(ws);
  k_main   <<<dim3(GRID), dim3(256), 0, stream>>>(
      box_cls, ctrness, locations, box_reg, pemb, pmar, pix, ws, out);
}

// Round 12
// 109.321 us; speedup vs baseline: 3.4177x; 1.8290x over previous
//
#include <hip/hip_runtime.h>
#include <cmath>

// EmbedMaskPostProcessor: top-k select + box decode + embedding-distance masks.
// Output [2,200,384,384] f32 = 236 MB, <1% nonzero -> write-BW bound (~34us floor).
// R12: geometric decoupling. locations<=764, box_reg<100 => decoded boxes clip
// to [0,767] => mask boxes live ONLY in the top-left 192x192 quadrant. So 3/4
// of the output (177 MB) is unconditionally zero, independent of selection:
//   node2: sel blocks (R8 pipeline, s_sleep(127) slow-poll barrier — R9/R11
//          showed hot spins co-running with the write stream collapse BW) +
//          zero blocks for the param-independent 177 MB. Overlap for free.
//   node3: per-(n,k) owner block f4-zeros its 192x192 quadrant, __syncthreads
//          (same-block, same-L2 => ordered), then patches box values.

namespace {
constexpr int NIMG = 2;
constexpr int NC   = 80;
constexpr int NHW  = 96 * 96;        // 9216
constexpr int NCHW = NC * NHW;       // 737280
constexpr int NDIM = 32;
constexpr int PH = 192, PW = 192;    // pixel_embed spatial
constexpr int OH = 384, OW = 384;    // output mask spatial
constexpr int KTOP = 200;
constexpr int CAP = 4096;            // gathered band candidates per image
constexpr int MCAP = 1024;           // member cap after 27-bit refine
constexpr int LCAP = 512;            // per-block gather buffer
constexpr float PRE_THRESH = 0.05f;
constexpr unsigned KEY_ZERO = 0x80000000u;  // key of +0.0f
constexpr float IMG_MAX = 767.0f;

constexpr int NBOX = NIMG * KTOP;    // 400
constexpr int ROW_F4 = OW / 4;       // 96 f4 per row
constexpr int MASK_F4 = OH * ROW_F4; // 36864 f4 per mask
constexpr int QF4 = 192 * 48;        // 9216 f4 in the 192x192 quadrant

constexpr int NZB = NBOX * 6;        // 2400 zero blocks (3 upper-right + 3 bottom)

constexpr int NF4 = NCHW / 4;        // 184320
constexpr int SEL_BLOCKS = 128;      // selection blocks per image
constexpr int NSEL = 2 * SEL_BLOCKS; // 256
constexpr int SEL_STRIDE = SEL_BLOCKS * 256;                    // 32768
constexpr int SEL_ITERS = (NF4 + SEL_STRIDE - 1) / SEL_STRIDE;  // 6

// ws layout (4-byte words); barrier/ticket/count words on separate 128B lines
// (R11 lesson: ticket atomics queued behind spin-loads on a shared line).
constexpr int WS_HIST1 = 0;                          // [NIMG][2048]
constexpr int WS_CNT   = 4096;                       // [NIMG]
constexpr int WS_BAR1  = 4128;                       // [1]
constexpr int WS_TICK  = 4160;                       // [NIMG]
constexpr int WS_ZERO_WORDS = 4224;
constexpr int WS_PAIRS = 4224;                       // [NIMG][CAP][2] {key,ref}
constexpr int WS_PARAMS = WS_PAIRS + NIMG * CAP * 2; // [NIMG][KTOP][40]
constexpr int PARAM_WORDS = 40;  // [0]=valid [1..4]=ix0,ix1,iy0,iy1 [5]=margin [8..39]=e

typedef float f4 __attribute__((ext_vector_type(4)));
}

__device__ __forceinline__ unsigned key_of(float f) {
  unsigned u = __float_as_uint(f);
  return (u & 0x80000000u) ? ~u : (u | 0x80000000u);  // monotone: bigger float -> bigger key
}
// sc1-bypass relaxed agent ops (device coherence point; no per-XCD L2 dirt).
__device__ __forceinline__ unsigned aget(const unsigned* p) {
  return __hip_atomic_load(p, __ATOMIC_RELAXED, __HIP_MEMORY_SCOPE_AGENT);
}
__device__ __forceinline__ void aput(unsigned* p, unsigned v) {
  __hip_atomic_store(p, v, __ATOMIC_RELAXED, __HIP_MEMORY_SCOPE_AGENT);
}

__global__ __launch_bounds__(256) void k_zero_ws(unsigned* __restrict__ ws) {
  for (int j = threadIdx.x; j < WS_ZERO_WORDS; j += 256) aput(ws + j, 0u);
}

// Node 2: blocks [0,256) selection; blocks [256, 256+NZB) zero the
// param-independent 3/4 of every mask (rows 0..191 x cols 192..383 + rows
// 192..383 full width).
__global__ __launch_bounds__(256) void k_node2(
    const float* __restrict__ box_cls, const float* __restrict__ ctrness,
    const float* __restrict__ locations, const float* __restrict__ box_reg,
    const float* __restrict__ pemb, const float* __restrict__ pmar,
    unsigned* __restrict__ ws, float* __restrict__ out) {
  const int t = threadIdx.x;
  const int bid = blockIdx.x;
  if (bid >= NSEL) {
    const int zb = bid - NSEL;
    const int nk = zb / 6;
    const int tile = zb - nk * 6;
    f4* base = reinterpret_cast<f4*>(out) + (size_t)nk * MASK_F4;
    const f4 z = {0.f, 0.f, 0.f, 0.f};
    if (tile < 3) {
      // upper-right: rows tile*64..+64, f4 cols 48..95 (bytes 768.. — separate
      // 128B lines from the quadrant; no cross-node WAW)
      f4* b = base + (tile * 64) * ROW_F4 + 48;
      #pragma unroll
      for (int i = 0; i < 12; ++i) {
        const int idx = i * 256 + t;            // 0..3071
        const int r = idx / 48;
        const int c = idx - r * 48;
        b[r * ROW_F4 + c] = z;
      }
    } else {
      // bottom half: rows 192+(tile-3)*64, full width, contiguous 96 KB
      f4* b = base + (192 + (tile - 3) * 64) * ROW_F4;
      #pragma unroll
      for (int i = 0; i < 24; ++i) b[i * 256 + t] = z;
    }
    return;
  }

  // ======== selection (R8 pipeline; slow-poll barrier) ========
  __shared__ unsigned hist[2048];
  __shared__ unsigned sh_sum[256];
  __shared__ int sh_bk[2];
  __shared__ unsigned loc[LCAP][2];
  __shared__ unsigned mKey[MCAP], mRef[MCAP];
  __shared__ unsigned h256[256];
  __shared__ int lcnt, sh_last, sh_b, sh_t2;
  __shared__ unsigned gbase;
  const int n = bid >= SEL_BLOCKS;
  const int bi = bid - n * SEL_BLOCKS;

  // ---- phase 1: keygen into registers + LDS hist (positives only) ----
  for (int i = t; i < 2048; i += 256) hist[i] = 0;
  __syncthreads();
  const float* cls = box_cls + n * NCHW;
  const float* ctr = ctrness + n * NHW;
  unsigned kk[SEL_ITERS][4];
  #pragma unroll
  for (int s = 0; s < SEL_ITERS; ++s) {
    const int j4 = s * SEL_STRIDE + bi * 256 + t;
    if (j4 < NF4) {
      const int j = j4 * 4;
      const int c = j / NHW;
      const int hw = j - c * NHW;                          // multiple of 4
      const f4 xv = *reinterpret_cast<const f4*>(cls + j);
      const f4 cv = *reinterpret_cast<const f4*>(ctr + hw);
      #pragma unroll
      for (int q = 0; q < 4; ++q) {
        const float sg = 1.0f / (1.0f + expf(-xv[q]));
        float v = -1.0f;
        if (sg > PRE_THRESH) v = sg * (1.0f / (1.0f + expf(-cv[q])));
        const unsigned k = key_of(v);
        kk[s][q] = k;
        if (k > KEY_ZERO) atomicAdd(&hist[k >> 21], 1u);
      }
    } else {
      #pragma unroll
      for (int q = 0; q < 4; ++q) kk[s][q] = 0u;
    }
  }
  __syncthreads();
  {
    unsigned* gh = ws + WS_HIST1 + n * 2048;
    for (int i = t; i < 2048; i += 256) { unsigned v = hist[i]; if (v) atomicAdd(&gh[i], v); }
  }

  // ---- barrier 1: relaxed arrive + SLOW poll (no spin storm vs write stream) ----
  __syncthreads();
  if (t == 0) {
    atomicAdd(ws + WS_BAR1, 1u);
    while (aget(ws + WS_BAR1) < (unsigned)NSEL) __builtin_amdgcn_s_sleep(127);
  }
  __syncthreads();

  // ---- phase 2: scan global hist (bypass loads) for b1/krem ----
  if (t == 0) { sh_bk[0] = -1; sh_bk[1] = KTOP; }
  {
    const unsigned* gh = ws + WS_HIST1 + n * 2048;
    unsigned local = 0;
    for (int j = 0; j < 8; ++j) { unsigned v = aget(gh + t * 8 + j); hist[t * 8 + j] = v; local += v; }
    sh_sum[t] = local;
  }
  __syncthreads();
  {
    unsigned S = 0;
    for (int j = t + 1; j < 256; ++j) S += sh_sum[j];
    int cand_b = -1;
    unsigned cand_above = 0;
    unsigned run = S;
    for (int j = 7; j >= 0; --j) {
      const unsigned cv = hist[t * 8 + j];
      if (cand_b < 0 && run + cv >= (unsigned)KTOP) { cand_b = t * 8 + j; cand_above = run; }
      run += cv;
    }
    if (cand_b >= 0) atomicMax(&sh_bk[0], cand_b);
    __syncthreads();
    if (cand_b >= 0 && cand_b == sh_bk[0]) sh_bk[1] = KTOP - (int)cand_above;
    __syncthreads();
  }
  const unsigned b1 = (unsigned)(sh_bk[0] < 0 ? 0 : sh_bk[0]);
  int krem = sh_bk[1];

  // ---- gather band members: regs -> LDS -> one global reservation ----
  if (t == 0) lcnt = 0;
  __syncthreads();
  #pragma unroll
  for (int s = 0; s < SEL_ITERS; ++s) {
    #pragma unroll
    for (int q = 0; q < 4; ++q) {
      const unsigned k = kk[s][q];
      if ((k >> 21) < b1) continue;
      const int j = (s * SEL_STRIDE + bi * 256 + t) * 4 + q;
      const int c = j / NHW;
      const int hw = j - c * NHW;
      const int p = atomicAdd(&lcnt, 1);
      if (p < LCAP) { loc[p][0] = k; loc[p][1] = (unsigned)(hw * NC + c); }
    }
  }
  __syncthreads();
  const int lc = min(lcnt, LCAP);
  if (t == 0) gbase = atomicAdd(ws + WS_CNT + n, (unsigned)lc);
  __syncthreads();
  for (int i = t; i < lc; i += 256) {
    const unsigned pos = gbase + (unsigned)i;
    if (pos < (unsigned)CAP) {
      aput(&ws[WS_PAIRS + (n * CAP + (int)pos) * 2], loc[i][0]);
      aput(&ws[WS_PAIRS + (n * CAP + (int)pos) * 2 + 1], loc[i][1]);
    }
  }

  // ---- per-image last-block ticket ----
  __syncthreads();
  if (t == 0) {
    const unsigned old = atomicAdd(ws + WS_TICK + n, 1u);
    sh_last = (old == (unsigned)(SEL_BLOCKS - 1)) ? 1 : 0;
  }
  __syncthreads();
  if (!sh_last) return;

  // ---- phase 3 (one block per image): refine to 27-bit prefix, compact,
  //      exact rank (value desc, index asc = lax.top_k), emit params ----
  for (int s = t; s < KTOP; s += 256) aput(&ws[WS_PARAMS + (n * KTOP + s) * PARAM_WORDS], 0u);
  const int cnt = min((int)aget(ws + WS_CNT + n), CAP);
  unsigned prefix = b1;
  int shift = 21;
  #pragma unroll
  for (int level = 0; level < 2; ++level) {
    const int newshift = shift - 8;
    h256[t] = 0;
    if (t == 0) sh_b = 0;
    __syncthreads();
    for (int i = t; i < cnt; i += 256) {
      const unsigned k = aget(&ws[WS_PAIRS + (n * CAP + i) * 2]);
      if ((k >> shift) == prefix) atomicAdd(&h256[(k >> newshift) & 255u], 1u);
    }
    __syncthreads();
    const unsigned hv = h256[t];
    unsigned S = 0;
    for (int j = t + 1; j < 256; ++j) S += h256[j];
    if (S + hv >= (unsigned)krem) atomicMax(&sh_b, t);
    __syncthreads();
    const int b = sh_b;
    if (t == b) sh_t2 = krem - (int)S;
    __syncthreads();
    krem = sh_t2;
    prefix = (prefix << 8) | (unsigned)b;
    shift = newshift;
    __syncthreads();
  }

  if (t == 0) sh_t2 = 0;
  __syncthreads();
  for (int i = t; i < cnt; i += 256) {
    const unsigned k = aget(&ws[WS_PAIRS + (n * CAP + i) * 2]);
    if ((k >> 5) >= prefix) {
      const int pos = atomicAdd(&sh_t2, 1);
      if (pos < MCAP) { mKey[pos] = k; mRef[pos] = aget(&ws[WS_PAIRS + (n * CAP + i) * 2 + 1]); }
    }
  }
  __syncthreads();
  const int m = min(sh_t2, MCAP);

  for (int i = t; i < m; i += 256) {
    const unsigned ki = mKey[i], ri = mRef[i];
    int rank = 0;
    for (int j = 0; j < m; ++j) {
      const unsigned kj = mKey[j], rj = mRef[j];
      rank += (kj > ki || (kj == ki && rj < ri)) ? 1 : 0;
    }
    if (rank >= KTOP) continue;
    unsigned* pp = ws + WS_PARAMS + (n * KTOP + rank) * PARAM_WORDS;
    int valid = 0;
    if (ki > KEY_ZERO) {
      const int hw = (int)ri / NC;
      const float lx = locations[2 * hw], ly = locations[2 * hw + 1];
      const float rl = box_reg[(n * 4 + 0) * NHW + hw];
      const float rt = box_reg[(n * 4 + 1) * NHW + hw];
      const float rr = box_reg[(n * 4 + 2) * NHW + hw];
      const float rb = box_reg[(n * 4 + 3) * NHW + hw];
      const float x1 = fminf(fmaxf(lx - rl, 0.f), IMG_MAX);
      const float y1 = fminf(fmaxf(ly - rt, 0.f), IMG_MAX);
      const float x2 = fminf(fmaxf(lx + rr, 0.f), IMG_MAX);
      const float y2 = fminf(fmaxf(ly + rb, 0.f), IMG_MAX);
      const int ix0 = max(0, (int)ceilf(x1 * 0.25f));
      const int ix1 = min(OW - 1, (int)floorf(x2 * 0.25f));
      const int iy0 = max(0, (int)ceilf(y1 * 0.25f));
      const int iy1 = min(OH - 1, (int)floorf(y2 * 0.25f));
      if (ix0 <= ix1 && iy0 <= iy1) {
        valid = 1;
        aput(pp + 1, (unsigned)ix0); aput(pp + 2, (unsigned)ix1);
        aput(pp + 3, (unsigned)iy0); aput(pp + 4, (unsigned)iy1);
        aput(pp + 5, __float_as_uint(pmar[n * NHW + hw]));
        #pragma unroll
        for (int d = 0; d < NDIM; ++d)
          aput(pp + 8 + d, __float_as_uint(pemb[(n * NDIM + d) * NHW + hw]));
      }
    }
    aput(pp + 0, (unsigned)valid);
  }
}

// Node 3: per-(n,k) owner. Pass A: f4-zero the 192x192 quadrant. __syncthreads
// (same block, same L2 -> pass-A stores complete & ordered). Pass B: patch
// in-box values with register-cached column walk (boxes proven to fit here:
// locations<=764, reg<100 -> x2,y2<=767 -> ix1,iy1<=191).
__global__ __launch_bounds__(256) void k_owner(const float* __restrict__ pix,
                                               const unsigned* __restrict__ ws,
                                               float* __restrict__ out) {
  const int nk = blockIdx.x;
  const int t = threadIdx.x;
  f4* q4 = reinterpret_cast<f4*>(out) + (size_t)nk * MASK_F4;
  const f4 z = {0.f, 0.f, 0.f, 0.f};
  #pragma unroll
  for (int i = 0; i < QF4 / 256; ++i) {      // 36 iters: rows 0..191, f4 cols 0..47
    const int idx = i * 256 + t;
    const int r = idx / 48;
    const int c = idx - r * 48;
    q4[r * ROW_F4 + c] = z;
  }
  const unsigned* meta = ws + WS_PARAMS + nk * PARAM_WORDS;
  const unsigned valid = aget(meta);
  __syncthreads();                           // drain pass-A stores (vmcnt) + order
  if (valid == 0u) return;
  const int ix0 = (int)aget(meta + 1), ix1 = (int)aget(meta + 2);
  const int iy0 = (int)aget(meta + 3), iy1 = (int)aget(meta + 4);
  const float margin = __uint_as_float(aget(meta + 5));
  float e[NDIM];
  #pragma unroll
  for (int d = 0; d < NDIM; ++d) e[d] = __uint_as_float(aget(meta + 8 + d));
  const int n = nk / KTOP;
  const float* peb = pix + (size_t)n * NDIM * PH * PW;
  float* ob = out + (size_t)nk * (OH * OW);

  const int tx = t & 63;             // column lane
  const int ts = t >> 6;             // row strip 0..3
  const int h = iy1 - iy0 + 1;
  const int shh = (h + 3) >> 2;
  const int ybeg = iy0 + ts * shh;
  const int yend = min(iy0 + (ts + 1) * shh, iy1 + 1);

  for (int c = ix0 + tx; c <= ix1; c += 64) {
    const float sx = 0.5f * (float)c - 0.25f;
    const float xf = floorf(sx);
    const float fx = sx - xf;
    const int xs0 = max((int)xf, 0);
    const int xs1 = min((int)xf + 1, PW - 1);
    float qa_[NDIM], qb_[NDIM];
    int ra = -9, rb = -9;
    for (int y = ybeg; y < yend; ++y) {
      const float sy = 0.5f * (float)y - 0.25f;
      const float yf = floorf(sy);
      const float fy = sy - yf;
      const int ys0 = max((int)yf, 0);
      const int ys1 = min((int)yf + 1, PH - 1);
      if (ys0 != ra) {
        if (ys0 == rb) {
          #pragma unroll
          for (int d = 0; d < NDIM; ++d) qa_[d] = qb_[d];
        } else {
          const float* p = peb + (size_t)ys0 * PW;
          #pragma unroll
          for (int d = 0; d < NDIM; ++d)
            qa_[d] = (1.f - fx) * p[d * PH * PW + xs0] + fx * p[d * PH * PW + xs1];
        }
        ra = ys0;
      }
      if (ys1 != rb) {
        if (ys1 == ra) {
          #pragma unroll
          for (int d = 0; d < NDIM; ++d) qb_[d] = qa_[d];
        } else {
          const float* p = peb + (size_t)ys1 * PW;
          #pragma unroll
          for (int d = 0; d < NDIM; ++d)
            qb_[d] = (1.f - fx) * p[d * PH * PW + xs0] + fx * p[d * PH * PW + xs1];
        }
        rb = ys1;
      }
      float d2 = 0.f;
      #pragma unroll
      for (int d = 0; d < NDIM; ++d) {
        const float pv = qa_[d] + fy * (qb_[d] - qa_[d]);
        const float df = e[d] - pv;
        d2 = fmaf(df, df, d2);
      }
      ob[(size_t)y * OW + c] = expf(-d2 * margin);
    }
  }
}

extern "C" void kernel_launch(void* const* d_in, const int* in_sizes, int n_in,
                              void* d_out, int out_size, void* d_ws, size_t ws_size,
                              hipStream_t stream) {
  const float* locations = (const float*)d_in[0];
  const float* box_cls   = (const float*)d_in[1];
  const float* box_reg   = (const float*)d_in[2];
  const float* ctrness   = (const float*)d_in[3];
  const float* pemb      = (const float*)d_in[4];
  const float* pmar      = (const float*)d_in[5];
  const float* pix       = (const float*)d_in[6];
  float* out = (float*)d_out;
  unsigned* ws = (unsigned*)d_ws;

  k_zero_ws<<<dim3(1), dim3(256), 0, stream>>>(ws);
  k_node2  <<<dim3(NSEL + NZB), dim3(256), 0, stream>>>(
      box_cls, ctrness, locations, box_reg, pemb, pmar, ws, out);
  k_owner  <<<dim3(NBOX), dim3(256), 0, stream>>>(pix, ws, out);
}